// Round 12
// baseline (278.166 us; speedup 1.0000x reference)
//
#include <hip/hip_runtime.h>
#include <hip/hip_bf16.h>
#include <stdint.h>

#define BB 4
#define TT 2048
#define CC 1024
#define HH 8
#define DD 128

typedef unsigned short u16;
typedef unsigned int u32;
typedef unsigned long long u64;
typedef __attribute__((ext_vector_type(4))) float f32x4;
typedef __attribute__((ext_vector_type(16))) float f32x16;
typedef __attribute__((ext_vector_type(8))) __bf16 bf16x8;

__device__ __forceinline__ float bf2f(u16 u){ u32 x=((u32)u)<<16; float f; __builtin_memcpy(&f,&x,4); return f; }
__device__ __forceinline__ u16 f2bf(float f){ u32 x; __builtin_memcpy(&x,&f,4); x += 0x7fffu + ((x>>16)&1u); return (u16)(x>>16); }

__device__ __forceinline__ void gload16(const void* g, void* l){
  __builtin_amdgcn_global_load_lds((const __attribute__((address_space(1))) u32*)g,
                                   (__attribute__((address_space(3))) u32*)l, 16, 0, 0);
}
__device__ __forceinline__ f32x4 mfma16(bf16x8 a, bf16x8 b, f32x4 c){
  return __builtin_amdgcn_mfma_f32_16x16x32_bf16(a,b,c,0,0,0);
}
__device__ __forceinline__ f32x16 mfma32(bf16x8 a, bf16x8 b, f32x16 c){
  return __builtin_amdgcn_mfma_f32_32x32x16_bf16(a,b,c,0,0,0);
}
__device__ __forceinline__ u32 cvtpk(float lo, float hi){
  u32 r; asm("v_cvt_pk_bf16_f32 %0, %1, %2" : "=v"(r) : "v"(lo), "v"(hi)); return r;
}
__device__ __forceinline__ void pl32swap(u32& d, u32& s){
  asm volatile("v_permlane32_swap_b32 %0, %1" : "+v"(d), "+v"(s));
}
union FRAG { u32 u[4]; bf16x8 v; };

// ---------------- LayerNorm: f32 x -> bf16 xn ----------------
__global__ void ln_k(const float* __restrict__ x, const float* __restrict__ g,
                     const float* __restrict__ bta, u16* __restrict__ xn){
  int row = blockIdx.x, tid = threadIdx.x;
  const float4 v = ((const float4*)(x + (size_t)row*CC))[tid];
  float s = v.x+v.y+v.z+v.w;
  float ss = v.x*v.x+v.y*v.y+v.z*v.z+v.w*v.w;
  #pragma unroll
  for(int m=1;m<64;m<<=1){ s += __shfl_xor(s,m); ss += __shfl_xor(ss,m); }
  __shared__ float red[8];
  if((tid&63)==0){ red[tid>>6]=s; red[4+(tid>>6)]=ss; }
  __syncthreads();
  float ts = red[0]+red[1]+red[2]+red[3];
  float tss = red[4]+red[5]+red[6]+red[7];
  float mu = ts*(1.0f/CC);
  float rs = rsqrtf(tss*(1.0f/CC) - mu*mu + 1e-5f);
  int c0 = tid*4;
  ushort4 o;
  o.x = f2bf((v.x-mu)*rs*g[c0+0]+bta[c0+0]);
  o.y = f2bf((v.y-mu)*rs*g[c0+1]+bta[c0+1]);
  o.z = f2bf((v.z-mu)*rs*g[c0+2]+bta[c0+2]);
  o.w = f2bf((v.w-mu)*rs*g[c0+3]+bta[c0+3]);
  ((ushort4*)(xn + (size_t)row*CC))[tid] = o;
}

// ---------------- weights f32 -> bf16 ----------------
__global__ void wconv_k(const float* __restrict__ wq, const float* __restrict__ wk,
                        const float* __restrict__ wv, const float* __restrict__ wo,
                        u16* __restrict__ out){
  int i = blockIdx.x*256 + threadIdx.x;
  int sel = i>>18;
  const float* src = sel==0?wq: sel==1?wk: sel==2?wv:wo;
  float4 v = ((const float4*)src)[i & 262143];
  ushort4 o; o.x=f2bf(v.x); o.y=f2bf(v.y); o.z=f2bf(v.z); o.w=f2bf(v.w);
  ((ushort4*)out)[i] = o;
}

// ---------------- RoPE tables ----------------
__global__ void rope_tab_k(float* __restrict__ cosT, float* __restrict__ sinT){
  int i = blockIdx.x*256 + threadIdx.x;
  int t = i>>6, j = i&63;
  float inv = powf(10000.0f, -(float)(2*j)*(1.0f/128.0f));
  float a = (float)t * inv;
  cosT[i] = cosf(a);
  sinT[i] = sinf(a);
}

// ---------------- qp/kp from RAW Q,K (rope applied locally to dims 0..2) ----------------
__global__ void qpkp_k(const u16* __restrict__ Qb, const u16* __restrict__ Kb,
                       const float* __restrict__ dirs, const float* __restrict__ cosT,
                       const float* __restrict__ sinT, float* __restrict__ qp, float* __restrict__ kp){
  int idx = blockIdx.x*256 + threadIdx.x;   // (b*H+h)*T + t
  int b = idx>>14, rem = idx & 16383;
  int h = rem>>11, t = rem & 2047;
  size_t base = ((size_t)(b*TT + t))*CC + h*DD;
  float qv = 0.f, kv = 0.f;
  #pragma unroll
  for(int d=0; d<3; d++){
    float c = cosT[t*64+d], s = sinT[t*64+d];
    float dr = dirs[h*3+d];
    qv += (bf2f(Qb[base+d])*c - bf2f(Qb[base+d+64])*s) * dr;
    kv += (bf2f(Kb[base+d])*c - bf2f(Kb[base+d+64])*s) * dr;
  }
  qp[idx] = qv; kp[idx] = kv;
}

// ---------------- RoPE: Q in place (pre-scaled by 1/sqrt(d)*log2e); K rope + pack to KF ----------------
__global__ void ropepack_k(u16* __restrict__ Qb, const u16* __restrict__ Kb,
                           u16* __restrict__ KF,
                           const float* __restrict__ cosT, const float* __restrict__ sinT){
  const float SL2 = 0.08838834764831845f * 1.442695040888963f;
  int bt = blockIdx.x, tid = threadIdx.x;   // 8192 x 128
  int b = bt>>11, t = bt & (TT-1);
  int ks = t>>5, k31 = t&31;
  #pragma unroll
  for(int pp=0; pp<4; pp++){
    int p = tid*4+pp;          // 0..511 = (h, d<64)
    int h = p>>6, d = p&63;
    size_t i1 = (size_t)bt*CC + h*DD + d;
    float c = cosT[t*64+d], s = sinT[t*64+d];
    float q1 = bf2f(Qb[i1]), q2 = bf2f(Qb[i1+64]);
    Qb[i1]    = f2bf((q1*c - q2*s)*SL2);
    Qb[i1+64] = f2bf((q2*c + q1*s)*SL2);
    float k1 = bf2f(Kb[i1]), k2 = bf2f(Kb[i1+64]);
    u16 kr1 = f2bf(k1*c - k2*s);
    u16 kr2 = f2bf(k2*c + k1*s);
    int bh = b*HH + h;
    int d2 = d + 64;
    size_t o1 = (((size_t)(bh*64 + ks)*8) + (d >>4))*512 + (((d >>3)&1)*32 + k31)*8 + (d &7);
    size_t o2 = (((size_t)(bh*64 + ks)*8) + (d2>>4))*512 + (((d2>>3)&1)*32 + k31)*8 + (d2&7);
    KF[o1] = kr1;
    KF[o2] = kr2;
  }
}

// ---------------- GEMM (R9-proven) ----------------
// MODE 0: bf16 row-major out. MODE 4: bf16 out packed to V-fragment order VF. MODE 2: f32 out + resid.
template<int MODE>
__global__ __launch_bounds__(256) void gemm_k(const u16* __restrict__ A, const u16* __restrict__ W,
                                              u16* __restrict__ outb, float* __restrict__ outf,
                                              const float* __restrict__ resid){
  __shared__ __align__(16) u16 As[128*64];
  __shared__ __align__(16) u16 Bs[128*64];
  const int K = CC;
  int m0 = blockIdx.x*128, n0 = blockIdx.y*128;
  int tid = threadIdx.x, w = tid>>6, l = tid&63;
  int li = l&15, lg = l>>4;
  int wm = w>>1, wn = w&1;
  f32x4 acc[4][4] = {};
  for(int k0=0; k0<K; k0+=64){
    #pragma unroll
    for(int i=0;i<4;i++){
      int L = (w*4+i)*1024 + l*16;
      int row = L>>7;
      int colb = (L&127) ^ ((row&7)<<4);
      gload16(A + ((size_t)(m0+row)*K + k0 + (colb>>1)), (char*)As + (w*4+i)*1024);
      gload16(W + ((size_t)(n0+row)*K + k0 + (colb>>1)), (char*)Bs + (w*4+i)*1024);
    }
    __syncthreads();
    #pragma unroll
    for(int kc=0;kc<2;kc++){
      bf16x8 af[4], bfr[4];
      #pragma unroll
      for(int mi=0;mi<4;mi++){
        int row = wm*64 + mi*16 + li;
        int colb = (kc*64 + lg*16) ^ ((row&7)<<4);
        af[mi] = *(const bf16x8*)((const char*)As + row*128 + colb);
      }
      #pragma unroll
      for(int ni=0;ni<4;ni++){
        int row = wn*64 + ni*16 + li;
        int colb = (kc*64 + lg*16) ^ ((row&7)<<4);
        bfr[ni] = *(const bf16x8*)((const char*)Bs + row*128 + colb);
      }
      #pragma unroll
      for(int mi=0;mi<4;mi++){
        #pragma unroll
        for(int ni=0;ni<4;ni++)
          acc[mi][ni] = mfma16(af[mi], bfr[ni], acc[mi][ni]);
      }
    }
    __syncthreads();
  }
  #pragma unroll
  for(int mi=0;mi<4;mi++){
    #pragma unroll
    for(int ni=0;ni<4;ni++){
      #pragma unroll
      for(int r=0;r<4;r++){
        int row = m0 + wm*64 + mi*16 + lg*4 + r;
        int col = n0 + wn*64 + ni*16 + li;
        float v = acc[mi][ni][r];
        if(MODE==0){
          outb[(size_t)row*CC + col] = f2bf(v);
        } else if(MODE==4){
          int t = row & 2047, b = row>>11;
          int h = col>>7, d = col&127;
          int bh = b*HH + h;
          size_t o = (((size_t)(bh*64 + (t>>5))*8) + (d>>5)*2 + ((t>>4)&1))*512
                     + (((t>>3)&1)*32 + (d&31))*8 + (t&7);
          outb[o] = f2bf(v);
        } else {
          size_t o = (size_t)row*CC + col;
          outf[o] = v + resid[o];
        }
      }
    }
  }
}

// ---------------- attention segment: proven body + per-wave LDS double-buffer prefetch ----------------
struct SegState { float m1, l1, m2, l2; f32x16 a1[4]; f32x16 a2[4]; };

__device__ __forceinline__ void run_seg(int t, int klo, int khi, int bh, int b, int h,
                                        int l5, int q31, int l,
                                        char* bufA, char* bufB,
                                        const u16* __restrict__ Q, const u16* __restrict__ KF,
                                        const u16* __restrict__ VF, const float* __restrict__ qp,
                                        const float* __restrict__ kp, SegState& S){
  const f32x16 zf = {};
  S.m1 = -__builtin_inff(); S.l1 = 0.f; S.m2 = -__builtin_inff(); S.l2 = 0.f;
  #pragma unroll
  for(int dt=0;dt<4;dt++){ S.a1[dt] = zf; S.a2[dt] = zf; }
  if(khi <= klo) return;

  int q0 = t*32, q = q0 + q31;
  bf16x8 qf[8];
  {
    const u16* qbase = Q + ((size_t)(b*TT + q)*CC + h*DD);
    #pragma unroll
    for(int db=0;db<8;db++) qf[db] = *(const bf16x8*)(qbase + db*16 + l5*8);
  }
  const float L2E = 1.442695040888963f;
  bf16x8 qpf;
  {
    float qs = qp[(size_t)bh*TT + q] * L2E;
    u16 qh = f2bf(qs); float qhf = bf2f(qh);
    u16 ql = f2bf(qs - qhf);
    FRAG fq; fq.u[0] = l5? 0u : ((u32)qh | ((u32)qh<<16));
    fq.u[1] = l5? 0u : (u32)ql; fq.u[2]=0; fq.u[3]=0;
    qpf = fq.v;
  }
  // per-lane global fragment sources (lane offset l*16B folded in)
  const u16* kfsrc = KF + (size_t)bh*64*4096 + (size_t)klo*4096 + (size_t)l*8;
  const u16* vfsrc = VF + (size_t)bh*64*4096 + (size_t)klo*4096 + (size_t)l*8;
  const float* kpp = kp + (size_t)bh*TT + q31;

  auto stage = [&](const u16* ks, const u16* vs, char* dst){
    #pragma unroll
    for(int c=0;c<8;c++) gload16(ks + c*512, dst + c*1024);
    #pragma unroll
    for(int c=0;c<8;c++) gload16(vs + c*512, dst + 8192 + c*1024);
  };

  stage(kfsrc, vfsrc, bufA);          // prologue: batch for klo
  kfsrc += 4096; vfsrc += 4096;
  char* cur = bufA; char* nxt = bufB;

  for(int is=klo; is<khi; ++is){
    int ksub = is*32;
    float kpv = kpp[ksub];
    if(is+1 < khi){
      stage(kfsrc, vfsrc, nxt);       // issue next batch (16 gload_lds, async)
      kfsrc += 4096; vfsrc += 4096;
      asm volatile("s_waitcnt vmcnt(16)" ::: "memory");   // current batch retired; next in flight
    } else {
      asm volatile("s_waitcnt vmcnt(0)" ::: "memory");
    }
    __builtin_amdgcn_sched_barrier(0);

    const u16* kbuf = (const u16*)cur;
    const u16* vbuf = (const u16*)(cur + 8192);
    bf16x8 kf0 = *(const bf16x8*)(kbuf + 0*512 + l*8);
    bf16x8 kf1 = *(const bf16x8*)(kbuf + 1*512 + l*8);
    bf16x8 kf2 = *(const bf16x8*)(kbuf + 2*512 + l*8);
    bf16x8 kf3 = *(const bf16x8*)(kbuf + 3*512 + l*8);
    bf16x8 kf4 = *(const bf16x8*)(kbuf + 4*512 + l*8);
    bf16x8 kf5 = *(const bf16x8*)(kbuf + 5*512 + l*8);
    bf16x8 kf6 = *(const bf16x8*)(kbuf + 6*512 + l*8);
    bf16x8 kf7 = *(const bf16x8*)(kbuf + 7*512 + l*8);

    f32x16 s0 = {}, s1a = {};
    __builtin_amdgcn_s_setprio(1);
    s0  = mfma32(kf0, qf[0], s0);  s1a = mfma32(kf1, qf[1], s1a);
    s0  = mfma32(kf2, qf[2], s0);  s1a = mfma32(kf3, qf[3], s1a);
    s0  = mfma32(kf4, qf[4], s0);  s1a = mfma32(kf5, qf[5], s1a);
    s0  = mfma32(kf6, qf[6], s0);  s1a = mfma32(kf7, qf[7], s1a);
    __builtin_amdgcn_s_setprio(0);

    f32x16 gg;
    {
      const f32x16 zf2 = {};
      u16 kh = f2bf(kpv); float khf = bf2f(kh);
      u16 kl = f2bf(kpv - khf);
      FRAG fk; fk.u[0] = l5? 0u : ((u32)kh | ((u32)kl<<16));
      fk.u[1] = l5? 0u : (u32)kh; fk.u[2]=0; fk.u[3]=0;
      gg = mfma32(fk.v, qpf, zf2);
    }

    float sv[16], gv[16];
    #pragma unroll
    for(int rr=0;rr<16;rr++){ sv[rr] = s0[rr]+s1a[rr]; gv[rr] = gg[rr]; }   // Q pre-scaled: log2 domain
    if(ksub + 31 > q0){                       // wave-uniform diagonal test
      #pragma unroll
      for(int rr=0;rr<16;rr++){
        int kg = ksub + (rr&3) + 8*(rr>>2) + 4*l5;
        if(kg > q){ sv[rr] = -__builtin_inff(); gv[rr] = -__builtin_inff(); }
      }
    }

    float mx=-__builtin_inff(), gx=-__builtin_inff();
    #pragma unroll
    for(int rr=0;rr<16;rr++){ mx = fmaxf(mx, sv[rr]); gx = fmaxf(gx, gv[rr]); }
    mx = fmaxf(mx, __shfl_xor(mx,32));
    gx = fmaxf(gx, __shfl_xor(gx,32));
    if(__ballot((mx > S.m1+8.f) | (gx > S.m2+8.f))){
      float mn1 = fmaxf(S.m1,mx), mn2 = fmaxf(S.m2,gx);
      float c1 = exp2f(S.m1-mn1), c2 = exp2f(S.m2-mn2);
      S.l1 *= c1; S.l2 *= c2; S.m1 = mn1; S.m2 = mn2;
      #pragma unroll
      for(int dt=0;dt<4;dt++){ S.a1[dt] *= c1; S.a2[dt] *= c2; }
    }
    float rs1=0.f, rs2=0.f;
    float e1[16], e2[16];
    #pragma unroll
    for(int rr=0;rr<16;rr++){
      e1[rr] = exp2f(sv[rr] - S.m1); rs1 += e1[rr];
      e2[rr] = exp2f(gv[rr] - S.m2); rs2 += e2[rr];
    }
    rs1 += __shfl_xor(rs1,32); rs2 += __shfl_xor(rs2,32);
    S.l1 += rs1; S.l2 += rs2;

    u32 P1[8], P2[8];
    #pragma unroll
    for(int m=0;m<8;m++){ P1[m] = cvtpk(e1[2*m], e1[2*m+1]); P2[m] = cvtpk(e2[2*m], e2[2*m+1]); }
    pl32swap(P1[0],P1[2]); pl32swap(P1[1],P1[3]); pl32swap(P1[4],P1[6]); pl32swap(P1[5],P1[7]);
    pl32swap(P2[0],P2[2]); pl32swap(P2[1],P2[3]); pl32swap(P2[4],P2[6]); pl32swap(P2[5],P2[7]);

    #pragma unroll
    for(int kb2=0;kb2<2;kb2++){
      FRAG f1, f2;
      #pragma unroll
      for(int j2=0;j2<4;j2++){ f1.u[j2] = P1[kb2*4+j2]; f2.u[j2] = P2[kb2*4+j2]; }
      bf16x8 pb1 = f1.v, pb2 = f2.v;
      bf16x8 vf0 = *(const bf16x8*)(vbuf + (0+kb2)*512 + l*8);
      bf16x8 vf1 = *(const bf16x8*)(vbuf + (2+kb2)*512 + l*8);
      bf16x8 vf2 = *(const bf16x8*)(vbuf + (4+kb2)*512 + l*8);
      bf16x8 vf3 = *(const bf16x8*)(vbuf + (6+kb2)*512 + l*8);
      __builtin_amdgcn_s_setprio(1);
      S.a1[0] = mfma32(vf0, pb1, S.a1[0]);  S.a2[0] = mfma32(vf0, pb2, S.a2[0]);
      S.a1[1] = mfma32(vf1, pb1, S.a1[1]);  S.a2[1] = mfma32(vf1, pb2, S.a2[1]);
      S.a1[2] = mfma32(vf2, pb1, S.a1[2]);  S.a2[2] = mfma32(vf2, pb2, S.a2[2]);
      S.a1[3] = mfma32(vf3, pb1, S.a1[3]);  S.a2[3] = mfma32(vf3, pb2, S.a2[3]);
      __builtin_amdgcn_s_setprio(0);
    }
    { char* tmp = cur; cur = nxt; nxt = tmp; }
  }
}

// ---------------- fused dual flash attention: R9 pair-balance + LDS prefetch ----------------
// 1024 blocks x 128 (2 waves). Wave0: tile p full + tile 63-p k[0,31-p) -> 32 iters; writes tile-p out,
// parks tile-(63-p) partial in LDS (overlays its own prefetch bufs, safe after loops).
// Wave1: tile 63-p k[31-p,64-p) -> 33 iters; merges + writes. launch_bounds(128,2): regs ~256/wave.
__global__ __launch_bounds__(128,2) void attn_k(const u16* __restrict__ Q, const u16* __restrict__ KF,
                                                const u16* __restrict__ VF, const float* __restrict__ qp,
                                                const float* __restrict__ kp, const float* __restrict__ hs,
                                                u16* __restrict__ outp){
  __shared__ __align__(16) char smem[66048];   // [0,64K): 4x16KB prefetch bufs; merge overlays wave0's half
  float* lp1 = (float*)smem;                   // 16 KB (overlay wave0 bufA)
  float* lp2 = (float*)(smem + 16384);         // 16 KB (overlay wave0 bufB)
  float* lml = (float*)(smem + 65536);         // 512 B
  int bid = blockIdx.x;
  int xcd = bid&7, r = bid>>3;          // r: 0..127
  int bh = xcd*4 + (r&3);               // 4 bh groups per XCD
  int p = r>>2;                         // 0..31 pair index
  int b = bh>>3, h = bh&7;
  int tid = threadIdx.x, w = tid>>6, l = tid&63;
  int l5 = l>>5, q31 = l&31;
  char* bufA = smem + w*32768;
  char* bufB = bufA + 16384;
  float sh = hs[h];

  SegState S;
  if(w==0){
    // seg0: tile p, full range, direct write
    run_seg(p, 0, p+1, bh, b, h, l5, q31, l, bufA, bufB, Q, KF, VF, qp, kp, S);
    {
      float rl1 = 1.0f/S.l1, rl2 = 1.0f/S.l2;
      int q = p*32 + q31;
      u16* obase = outp + (size_t)(b*TT + q)*CC + h*DD;
      #pragma unroll
      for(int dt=0;dt<4;dt++){
        #pragma unroll
        for(int m=0;m<8;m++){
          float oa1 = S.a1[dt][2*m]*rl1,   oa2 = S.a2[dt][2*m]*rl2;
          float ob1 = S.a1[dt][2*m+1]*rl1, ob2 = S.a2[dt][2*m+1]*rl2;
          float oa = oa1 + sh*(oa2-oa1);
          float ob = ob1 + sh*(ob2-ob1);
          int d = dt*32 + (2*m&3) + 8*(m>>1) + 4*l5;
          *(u32*)(obase + d) = cvtpk(oa, ob);
        }
      }
    }
    // seg1: tile 63-p, first half k[0, 31-p) -> partial parked in LDS (own bufs, loops done)
    run_seg(63-p, 0, 31-p, bh, b, h, l5, q31, l, bufA, bufB, Q, KF, VF, qp, kp, S);
    #pragma unroll
    for(int dt=0;dt<4;dt++){
      *(f32x16*)&lp1[(dt*64 + l)*16] = S.a1[dt];
      *(f32x16*)&lp2[(dt*64 + l)*16] = S.a2[dt];
    }
    if(l5==0){
      lml[q31*4+0] = S.m1; lml[q31*4+1] = S.l1;
      lml[q31*4+2] = S.m2; lml[q31*4+3] = S.l2;
    }
    __syncthreads();
  } else {
    // wave1: tile 63-p, second half k[31-p, 64-p)
    run_seg(63-p, 31-p, 64-p, bh, b, h, l5, q31, l, bufA, bufB, Q, KF, VF, qp, kp, S);
    __syncthreads();
    float mA1 = lml[q31*4+0], lA1 = lml[q31*4+1];
    float mA2 = lml[q31*4+2], lA2 = lml[q31*4+3];
    float M1 = fmaxf(mA1, S.m1), M2 = fmaxf(mA2, S.m2);
    float wA1 = exp2f(mA1-M1), wB1 = exp2f(S.m1-M1);
    float wA2 = exp2f(mA2-M2), wB2 = exp2f(S.m2-M2);
    float r1 = 1.0f/(wA1*lA1 + wB1*S.l1);
    float r2 = 1.0f/(wA2*lA2 + wB2*S.l2);
    int q = (63-p)*32 + q31;
    u16* obase = outp + (size_t)(b*TT + q)*CC + h*DD;
    #pragma unroll
    for(int dt=0;dt<4;dt++){
      f32x16 pa1 = *(const f32x16*)&lp1[(dt*64 + l)*16];
      f32x16 pa2 = *(const f32x16*)&lp2[(dt*64 + l)*16];
      #pragma unroll
      for(int m=0;m<8;m++){
        float oa1 = (wA1*pa1[2*m]   + wB1*S.a1[dt][2*m])*r1;
        float ob1 = (wA1*pa1[2*m+1] + wB1*S.a1[dt][2*m+1])*r1;
        float oa2 = (wA2*pa2[2*m]   + wB2*S.a2[dt][2*m])*r2;
        float ob2 = (wA2*pa2[2*m+1] + wB2*S.a2[dt][2*m+1])*r2;
        float oa = oa1 + sh*(oa2-oa1);
        float ob = ob1 + sh*(ob2-ob1);
        int d = dt*32 + (2*m&3) + 8*(m>>1) + 4*l5;
        *(u32*)(obase + d) = cvtpk(oa, ob);
      }
    }
  }
}

extern "C" void kernel_launch(void* const* d_in, const int* in_sizes, int n_in,
                              void* d_out, int out_size, void* d_ws, size_t ws_size,
                              hipStream_t stream){
  (void)in_sizes; (void)n_in; (void)out_size; (void)ws_size;
  const float* x   = (const float*)d_in[0];
  const float* Wq  = (const float*)d_in[1];
  const float* Wk  = (const float*)d_in[2];
  const float* Wv  = (const float*)d_in[3];
  const float* Wo  = (const float*)d_in[4];
  const float* lng = (const float*)d_in[5];
  const float* lnb = (const float*)d_in[6];
  const float* hsc = (const float*)d_in[7];
  const float* hdr = (const float*)d_in[8];

  char* ws = (char*)d_ws;
  const size_t MB = 1048576;
  u16* xn   = (u16*)ws;                 // 16MB (LN out, later attn out)
  u16* wbf  = (u16*)(ws + 16*MB);       // 8MB bf16 weights Wq|Wk|Wv|Wo
  u16* Qb   = (u16*)(ws + 24*MB);       // 16MB
  u16* Kb   = (u16*)(ws + 40*MB);       // 16MB raw K
  u16* VF   = (u16*)(ws + 56*MB);       // 16MB packed V fragments
  u16* KF   = (u16*)(ws + 72*MB);       // 16MB packed K fragments
  float* cosT = (float*)(ws + 88*MB);
  float* sinT = cosT + 131072;
  float* qp   = sinT + 131072;
  float* kp   = qp + 65536;

  ln_k<<<8192,256,0,stream>>>(x, lng, lnb, xn);
  wconv_k<<<4096,256,0,stream>>>(Wq,Wk,Wv,Wo,wbf);
  rope_tab_k<<<512,256,0,stream>>>(cosT,sinT);
  gemm_k<0><<<dim3(64,8),256,0,stream>>>(xn, wbf,          Qb, nullptr, nullptr);
  gemm_k<0><<<dim3(64,8),256,0,stream>>>(xn, wbf+1048576,  Kb, nullptr, nullptr);
  gemm_k<4><<<dim3(64,8),256,0,stream>>>(xn, wbf+2097152,  VF, nullptr, nullptr);
  qpkp_k<<<256,256,0,stream>>>(Qb,Kb,hdr,cosT,sinT,qp,kp);          // raw Q/K + local rope
  ropepack_k<<<8192,128,0,stream>>>(Qb,Kb,KF,cosT,sinT);            // Q in place (pre-scaled); K -> KF
  attn_k<<<1024,128,0,stream>>>(Qb,KF,VF,qp,kp,hsc,xn);
  gemm_k<2><<<dim3(64,8),256,0,stream>>>(xn, wbf+3145728, nullptr, (float*)d_out, x);
}

// Round 13
// 230.348 us; speedup vs baseline: 1.2076x; 1.2076x over previous
//
#include <hip/hip_runtime.h>
#include <hip/hip_bf16.h>
#include <stdint.h>

#define BB 4
#define TT 2048
#define CC 1024
#define HH 8
#define DD 128

typedef unsigned short u16;
typedef unsigned int u32;
typedef unsigned long long u64;
typedef __attribute__((ext_vector_type(4))) float f32x4;
typedef __attribute__((ext_vector_type(16))) float f32x16;
typedef __attribute__((ext_vector_type(8))) __bf16 bf16x8;

__device__ __forceinline__ float bf2f(u16 u){ u32 x=((u32)u)<<16; float f; __builtin_memcpy(&f,&x,4); return f; }
__device__ __forceinline__ u16 f2bf(float f){ u32 x; __builtin_memcpy(&x,&f,4); x += 0x7fffu + ((x>>16)&1u); return (u16)(x>>16); }

__device__ __forceinline__ void gload16(const void* g, void* l){
  __builtin_amdgcn_global_load_lds((const __attribute__((address_space(1))) u32*)g,
                                   (__attribute__((address_space(3))) u32*)l, 16, 0, 0);
}
__device__ __forceinline__ f32x4 mfma16(bf16x8 a, bf16x8 b, f32x4 c){
  return __builtin_amdgcn_mfma_f32_16x16x32_bf16(a,b,c,0,0,0);
}
__device__ __forceinline__ f32x16 mfma32(bf16x8 a, bf16x8 b, f32x16 c){
  return __builtin_amdgcn_mfma_f32_32x32x16_bf16(a,b,c,0,0,0);
}
__device__ __forceinline__ u32 cvtpk(float lo, float hi){
  u32 r; asm("v_cvt_pk_bf16_f32 %0, %1, %2" : "=v"(r) : "v"(lo), "v"(hi)); return r;
}
__device__ __forceinline__ void pl32swap(u32& d, u32& s){
  asm volatile("v_permlane32_swap_b32 %0, %1" : "+v"(d), "+v"(s));
}
union FRAG { u32 u[4]; bf16x8 v; };

// ---------------- LayerNorm: f32 x -> bf16 xn ----------------
__global__ void ln_k(const float* __restrict__ x, const float* __restrict__ g,
                     const float* __restrict__ bta, u16* __restrict__ xn){
  int row = blockIdx.x, tid = threadIdx.x;
  const float4 v = ((const float4*)(x + (size_t)row*CC))[tid];
  float s = v.x+v.y+v.z+v.w;
  float ss = v.x*v.x+v.y*v.y+v.z*v.z+v.w*v.w;
  #pragma unroll
  for(int m=1;m<64;m<<=1){ s += __shfl_xor(s,m); ss += __shfl_xor(ss,m); }
  __shared__ float red[8];
  if((tid&63)==0){ red[tid>>6]=s; red[4+(tid>>6)]=ss; }
  __syncthreads();
  float ts = red[0]+red[1]+red[2]+red[3];
  float tss = red[4]+red[5]+red[6]+red[7];
  float mu = ts*(1.0f/CC);
  float rs = rsqrtf(tss*(1.0f/CC) - mu*mu + 1e-5f);
  int c0 = tid*4;
  ushort4 o;
  o.x = f2bf((v.x-mu)*rs*g[c0+0]+bta[c0+0]);
  o.y = f2bf((v.y-mu)*rs*g[c0+1]+bta[c0+1]);
  o.z = f2bf((v.z-mu)*rs*g[c0+2]+bta[c0+2]);
  o.w = f2bf((v.w-mu)*rs*g[c0+3]+bta[c0+3]);
  ((ushort4*)(xn + (size_t)row*CC))[tid] = o;
}

// ---------------- weights f32 -> bf16 ----------------
__global__ void wconv_k(const float* __restrict__ wq, const float* __restrict__ wk,
                        const float* __restrict__ wv, const float* __restrict__ wo,
                        u16* __restrict__ out){
  int i = blockIdx.x*256 + threadIdx.x;
  int sel = i>>18;
  const float* src = sel==0?wq: sel==1?wk: sel==2?wv:wo;
  float4 v = ((const float4*)src)[i & 262143];
  ushort4 o; o.x=f2bf(v.x); o.y=f2bf(v.y); o.z=f2bf(v.z); o.w=f2bf(v.w);
  ((ushort4*)out)[i] = o;
}

// ---------------- RoPE tables ----------------
__global__ void rope_tab_k(float* __restrict__ cosT, float* __restrict__ sinT){
  int i = blockIdx.x*256 + threadIdx.x;
  int t = i>>6, j = i&63;
  float inv = powf(10000.0f, -(float)(2*j)*(1.0f/128.0f));
  float a = (float)t * inv;
  cosT[i] = cosf(a);
  sinT[i] = sinf(a);
}

// ---------------- qp/kp from RAW Q,K (rope applied locally to dims 0..2) ----------------
__global__ void qpkp_k(const u16* __restrict__ Qb, const u16* __restrict__ Kb,
                       const float* __restrict__ dirs, const float* __restrict__ cosT,
                       const float* __restrict__ sinT, float* __restrict__ qp, float* __restrict__ kp){
  int idx = blockIdx.x*256 + threadIdx.x;   // (b*H+h)*T + t
  int b = idx>>14, rem = idx & 16383;
  int h = rem>>11, t = rem & 2047;
  size_t base = ((size_t)(b*TT + t))*CC + h*DD;
  float qv = 0.f, kv = 0.f;
  #pragma unroll
  for(int d=0; d<3; d++){
    float c = cosT[t*64+d], s = sinT[t*64+d];
    float dr = dirs[h*3+d];
    qv += (bf2f(Qb[base+d])*c - bf2f(Qb[base+d+64])*s) * dr;
    kv += (bf2f(Kb[base+d])*c - bf2f(Kb[base+d+64])*s) * dr;
  }
  qp[idx] = qv; kp[idx] = kv;
}

// ---------------- RoPE: Q in place (pre-scaled by 1/sqrt(d)*log2e); K rope + pack to KF ----------------
// Vectorized: each thread does 4 consecutive d -> ushort4 loads/stores (KF offsets proven consecutive).
__global__ void ropepack_k(u16* __restrict__ Qb, const u16* __restrict__ Kb,
                           u16* __restrict__ KF,
                           const float* __restrict__ cosT, const float* __restrict__ sinT){
  const float SL2 = 0.08838834764831845f * 1.442695040888963f;
  int bt = blockIdx.x, tid = threadIdx.x;   // 8192 x 128
  int b = bt>>11, t = bt & (TT-1);
  int ks = t>>5, k31 = t&31;
  int p0 = tid*4;            // (h, d0) with d0 % 4 == 0
  int h = p0>>6, d0 = p0&63;
  size_t i1 = (size_t)bt*CC + h*DD + d0;
  ushort4 q1v = *(const ushort4*)(Qb + i1);
  ushort4 q2v = *(const ushort4*)(Qb + i1 + 64);
  ushort4 k1v = *(const ushort4*)(Kb + i1);
  ushort4 k2v = *(const ushort4*)(Kb + i1 + 64);
  float4 cv = *(const float4*)(cosT + t*64 + d0);
  float4 sv = *(const float4*)(sinT + t*64 + d0);
  float q1[4] = {bf2f(q1v.x),bf2f(q1v.y),bf2f(q1v.z),bf2f(q1v.w)};
  float q2[4] = {bf2f(q2v.x),bf2f(q2v.y),bf2f(q2v.z),bf2f(q2v.w)};
  float k1[4] = {bf2f(k1v.x),bf2f(k1v.y),bf2f(k1v.z),bf2f(k1v.w)};
  float k2[4] = {bf2f(k2v.x),bf2f(k2v.y),bf2f(k2v.z),bf2f(k2v.w)};
  float cc[4] = {cv.x,cv.y,cv.z,cv.w};
  float ssn[4] = {sv.x,sv.y,sv.z,sv.w};
  ushort4 oq1, oq2, ok1, ok2;
  u16* oq1p = (u16*)&oq1; u16* oq2p = (u16*)&oq2;
  u16* ok1p = (u16*)&ok1; u16* ok2p = (u16*)&ok2;
  #pragma unroll
  for(int j=0;j<4;j++){
    oq1p[j] = f2bf((q1[j]*cc[j] - q2[j]*ssn[j])*SL2);
    oq2p[j] = f2bf((q2[j]*cc[j] + q1[j]*ssn[j])*SL2);
    ok1p[j] = f2bf(k1[j]*cc[j] - k2[j]*ssn[j]);
    ok2p[j] = f2bf(k2[j]*cc[j] + k1[j]*ssn[j]);
  }
  *(ushort4*)(Qb + i1)      = oq1;
  *(ushort4*)(Qb + i1 + 64) = oq2;
  int bh = b*HH + h;
  int d2 = d0 + 64;
  size_t o1 = (((size_t)(bh*64 + ks)*8) + (d0>>4))*512 + (((d0>>3)&1)*32 + k31)*8 + (d0&7);
  size_t o2 = (((size_t)(bh*64 + ks)*8) + (d2>>4))*512 + (((d2>>3)&1)*32 + k31)*8 + (d2&7);
  *(ushort4*)(KF + o1) = ok1;
  *(ushort4*)(KF + o2) = ok2;
}

// ---------------- GEMM (R9-proven; MODE 4 epilogue packed to 8B stores) ----------------
// MODE 0: bf16 row-major out. MODE 4: bf16 out packed to V-fragment order VF. MODE 2: f32 out + resid.
template<int MODE>
__global__ __launch_bounds__(256) void gemm_k(const u16* __restrict__ A, const u16* __restrict__ W,
                                              u16* __restrict__ outb, float* __restrict__ outf,
                                              const float* __restrict__ resid){
  __shared__ __align__(16) u16 As[128*64];
  __shared__ __align__(16) u16 Bs[128*64];
  const int K = CC;
  int m0 = blockIdx.x*128, n0 = blockIdx.y*128;
  int tid = threadIdx.x, w = tid>>6, l = tid&63;
  int li = l&15, lg = l>>4;
  int wm = w>>1, wn = w&1;
  f32x4 acc[4][4] = {};
  for(int k0=0; k0<K; k0+=64){
    #pragma unroll
    for(int i=0;i<4;i++){
      int L = (w*4+i)*1024 + l*16;
      int row = L>>7;
      int colb = (L&127) ^ ((row&7)<<4);
      gload16(A + ((size_t)(m0+row)*K + k0 + (colb>>1)), (char*)As + (w*4+i)*1024);
      gload16(W + ((size_t)(n0+row)*K + k0 + (colb>>1)), (char*)Bs + (w*4+i)*1024);
    }
    __syncthreads();
    #pragma unroll
    for(int kc=0;kc<2;kc++){
      bf16x8 af[4], bfr[4];
      #pragma unroll
      for(int mi=0;mi<4;mi++){
        int row = wm*64 + mi*16 + li;
        int colb = (kc*64 + lg*16) ^ ((row&7)<<4);
        af[mi] = *(const bf16x8*)((const char*)As + row*128 + colb);
      }
      #pragma unroll
      for(int ni=0;ni<4;ni++){
        int row = wn*64 + ni*16 + li;
        int colb = (kc*64 + lg*16) ^ ((row&7)<<4);
        bfr[ni] = *(const bf16x8*)((const char*)Bs + row*128 + colb);
      }
      #pragma unroll
      for(int mi=0;mi<4;mi++){
        #pragma unroll
        for(int ni=0;ni<4;ni++)
          acc[mi][ni] = mfma16(af[mi], bfr[ni], acc[mi][ni]);
      }
    }
    __syncthreads();
  }
  #pragma unroll
  for(int mi=0;mi<4;mi++){
    #pragma unroll
    for(int ni=0;ni<4;ni++){
      if(MODE==4){
        // 4 r-values map to consecutive VF offsets (t&7 increments; higher bits constant; 8B aligned)
        int row0 = m0 + wm*64 + mi*16 + lg*4;
        int col = n0 + wn*64 + ni*16 + li;
        int t = row0 & 2047, b = row0>>11;
        int h = col>>7, d = col&127;
        int bh = b*HH + h;
        size_t o = (((size_t)(bh*64 + (t>>5))*8) + (d>>5)*2 + ((t>>4)&1))*512
                   + (((t>>3)&1)*32 + (d&31))*8 + (t&7);
        ushort4 pk;
        pk.x = f2bf(acc[mi][ni][0]); pk.y = f2bf(acc[mi][ni][1]);
        pk.z = f2bf(acc[mi][ni][2]); pk.w = f2bf(acc[mi][ni][3]);
        *(ushort4*)(outb + o) = pk;
      } else {
        #pragma unroll
        for(int r=0;r<4;r++){
          int row = m0 + wm*64 + mi*16 + lg*4 + r;
          int col = n0 + wn*64 + ni*16 + li;
          float v = acc[mi][ni][r];
          if(MODE==0){
            outb[(size_t)row*CC + col] = f2bf(v);
          } else {
            size_t o = (size_t)row*CC + col;
            outf[o] = v + resid[o];
          }
        }
      }
    }
  }
}

// ---------------- attention segment state + inner loop (R11-proven body, Q pre-scaled) ----------------
struct SegState { float m1, l1, m2, l2; f32x16 a1[4]; f32x16 a2[4]; };

__device__ __forceinline__ void run_seg(int t, int klo, int khi, int bh, int b, int h,
                                        int l5, int q31,
                                        const u16* __restrict__ Q, const u16* __restrict__ KF,
                                        const u16* __restrict__ VF, const float* __restrict__ qp,
                                        const float* __restrict__ kp, SegState& S){
  const f32x16 zf = {};
  S.m1 = -__builtin_inff(); S.l1 = 0.f; S.m2 = -__builtin_inff(); S.l2 = 0.f;
  #pragma unroll
  for(int dt=0;dt<4;dt++){ S.a1[dt] = zf; S.a2[dt] = zf; }
  if(khi <= klo) return;

  int q0 = t*32, q = q0 + q31;
  bf16x8 qf[8];
  {
    const u16* qbase = Q + ((size_t)(b*TT + q)*CC + h*DD);
    #pragma unroll
    for(int db=0;db<8;db++) qf[db] = *(const bf16x8*)(qbase + db*16 + l5*8);
  }
  const float L2E = 1.442695040888963f;
  bf16x8 qpf;
  {
    float qs = qp[(size_t)bh*TT + q] * L2E;
    u16 qh = f2bf(qs); float qhf = bf2f(qh);
    u16 ql = f2bf(qs - qhf);
    FRAG fq; fq.u[0] = l5? 0u : ((u32)qh | ((u32)qh<<16));
    fq.u[1] = l5? 0u : (u32)ql; fq.u[2]=0; fq.u[3]=0;
    qpf = fq.v;
  }
  const u16* kfp = KF + (size_t)bh*64*4096 + (size_t)klo*4096 + (size_t)(q31 + 32*l5)*8;
  const u16* vfp = VF + (size_t)bh*64*4096 + (size_t)klo*4096 + (size_t)(q31 + 32*l5)*8;
  const float* kpp = kp + (size_t)bh*TT + q31;

  for(int is=klo; is<khi; ++is){
    int ksub = is*32;

    bf16x8 kf0 = *(const bf16x8*)(kfp + 0*512);
    bf16x8 kf1 = *(const bf16x8*)(kfp + 1*512);
    bf16x8 kf2 = *(const bf16x8*)(kfp + 2*512);
    bf16x8 kf3 = *(const bf16x8*)(kfp + 3*512);
    bf16x8 kf4 = *(const bf16x8*)(kfp + 4*512);
    bf16x8 kf5 = *(const bf16x8*)(kfp + 5*512);
    bf16x8 kf6 = *(const bf16x8*)(kfp + 6*512);
    bf16x8 kf7 = *(const bf16x8*)(kfp + 7*512);

    f32x16 s0 = {}, s1a = {};
    __builtin_amdgcn_s_setprio(1);
    s0  = mfma32(kf0, qf[0], s0);  s1a = mfma32(kf1, qf[1], s1a);
    s0  = mfma32(kf2, qf[2], s0);  s1a = mfma32(kf3, qf[3], s1a);
    s0  = mfma32(kf4, qf[4], s0);  s1a = mfma32(kf5, qf[5], s1a);
    s0  = mfma32(kf6, qf[6], s0);  s1a = mfma32(kf7, qf[7], s1a);
    __builtin_amdgcn_s_setprio(0);

    f32x16 gg;
    {
      const f32x16 zf2 = {};
      float kpv = kpp[ksub];
      u16 kh = f2bf(kpv); float khf = bf2f(kh);
      u16 kl = f2bf(kpv - khf);
      FRAG fk; fk.u[0] = l5? 0u : ((u32)kh | ((u32)kl<<16));
      fk.u[1] = l5? 0u : (u32)kh; fk.u[2]=0; fk.u[3]=0;
      gg = mfma32(fk.v, qpf, zf2);
    }

    float sv[16], gv[16];
    #pragma unroll
    for(int rr=0;rr<16;rr++){ sv[rr] = s0[rr]+s1a[rr]; gv[rr] = gg[rr]; }   // Q pre-scaled: log2 domain
    if(ksub + 31 > q0){                       // wave-uniform diagonal test
      #pragma unroll
      for(int rr=0;rr<16;rr++){
        int kg = ksub + (rr&3) + 8*(rr>>2) + 4*l5;
        if(kg > q){ sv[rr] = -__builtin_inff(); gv[rr] = -__builtin_inff(); }
      }
    }

    float mx=-__builtin_inff(), gx=-__builtin_inff();
    #pragma unroll
    for(int rr=0;rr<16;rr++){ mx = fmaxf(mx, sv[rr]); gx = fmaxf(gx, gv[rr]); }
    mx = fmaxf(mx, __shfl_xor(mx,32));
    gx = fmaxf(gx, __shfl_xor(gx,32));
    if(__ballot((mx > S.m1+8.f) | (gx > S.m2+8.f))){
      float mn1 = fmaxf(S.m1,mx), mn2 = fmaxf(S.m2,gx);
      float c1 = exp2f(S.m1-mn1), c2 = exp2f(S.m2-mn2);
      S.l1 *= c1; S.l2 *= c2; S.m1 = mn1; S.m2 = mn2;
      #pragma unroll
      for(int dt=0;dt<4;dt++){ S.a1[dt] *= c1; S.a2[dt] *= c2; }
    }
    float rs1=0.f, rs2=0.f;
    float e1[16], e2[16];
    #pragma unroll
    for(int rr=0;rr<16;rr++){
      e1[rr] = exp2f(sv[rr] - S.m1); rs1 += e1[rr];
      e2[rr] = exp2f(gv[rr] - S.m2); rs2 += e2[rr];
    }
    rs1 += __shfl_xor(rs1,32); rs2 += __shfl_xor(rs2,32);
    S.l1 += rs1; S.l2 += rs2;

    u32 P1[8], P2[8];
    #pragma unroll
    for(int m=0;m<8;m++){ P1[m] = cvtpk(e1[2*m], e1[2*m+1]); P2[m] = cvtpk(e2[2*m], e2[2*m+1]); }
    pl32swap(P1[0],P1[2]); pl32swap(P1[1],P1[3]); pl32swap(P1[4],P1[6]); pl32swap(P1[5],P1[7]);
    pl32swap(P2[0],P2[2]); pl32swap(P2[1],P2[3]); pl32swap(P2[4],P2[6]); pl32swap(P2[5],P2[7]);

    #pragma unroll
    for(int kb2=0;kb2<2;kb2++){
      FRAG f1, f2;
      #pragma unroll
      for(int j2=0;j2<4;j2++){ f1.u[j2] = P1[kb2*4+j2]; f2.u[j2] = P2[kb2*4+j2]; }
      bf16x8 pb1 = f1.v, pb2 = f2.v;
      bf16x8 vf0 = *(const bf16x8*)(vfp + (0+kb2)*512);
      bf16x8 vf1 = *(const bf16x8*)(vfp + (2+kb2)*512);
      bf16x8 vf2 = *(const bf16x8*)(vfp + (4+kb2)*512);
      bf16x8 vf3 = *(const bf16x8*)(vfp + (6+kb2)*512);
      __builtin_amdgcn_s_setprio(1);
      S.a1[0] = mfma32(vf0, pb1, S.a1[0]);  S.a2[0] = mfma32(vf0, pb2, S.a2[0]);
      S.a1[1] = mfma32(vf1, pb1, S.a1[1]);  S.a2[1] = mfma32(vf1, pb2, S.a2[1]);
      S.a1[2] = mfma32(vf2, pb1, S.a1[2]);  S.a2[2] = mfma32(vf2, pb2, S.a2[2]);
      S.a1[3] = mfma32(vf3, pb1, S.a1[3]);  S.a2[3] = mfma32(vf3, pb2, S.a2[3]);
      __builtin_amdgcn_s_setprio(0);
    }
    kfp += 4096; vfp += 4096;
  }
}

// ---------------- fused dual flash attention: pair-balanced waves + in-block LDS merge (R9/R11-proven) ----------------
// 1024 blocks x 128 (2 waves). Block = (bh, pair p). Wave0: tile p full (p+1) + tile 63-p k[0,31-p) -> 32 iters.
// Wave1: tile 63-p k[31-p,64-p) -> 33 iters. Tile 63-p merged via LDS (LSE-weighted), single barrier.
// NOTE: keep __launch_bounds__(128,2) — combined VGPR+AGPR/wave ~256 (unified file): 3/EU spills (R6/R7);
// adding prefetch machinery bloats VGPR to 208 and halves occupancy (R12). Do not touch.
__global__ __launch_bounds__(128,2) void attn_k(const u16* __restrict__ Q, const u16* __restrict__ KF,
                                                const u16* __restrict__ VF, const float* __restrict__ qp,
                                                const float* __restrict__ kp, const float* __restrict__ hs,
                                                u16* __restrict__ outp){
  __shared__ __align__(16) float lp1[4*64*16];   // wave0's partial a1 [dt][lane][r]
  __shared__ __align__(16) float lp2[4*64*16];   // partial a2
  __shared__ float lml[32*4];                    // per q31: m1,l1,m2,l2
  int bid = blockIdx.x;
  int xcd = bid&7, r = bid>>3;          // r: 0..127
  int bh = xcd*4 + (r&3);               // 4 bh groups per XCD
  int p = r>>2;                         // 0..31 pair index
  int b = bh>>3, h = bh&7;
  int tid = threadIdx.x, w = tid>>6, l = tid&63;
  int l5 = l>>5, q31 = l&31;
  float sh = hs[h];

  SegState S;
  if(w==0){
    // seg0: tile p, full range, direct write
    run_seg(p, 0, p+1, bh, b, h, l5, q31, Q, KF, VF, qp, kp, S);
    {
      float rl1 = 1.0f/S.l1, rl2 = 1.0f/S.l2;
      int q = p*32 + q31;
      u16* obase = outp + (size_t)(b*TT + q)*CC + h*DD;
      #pragma unroll
      for(int dt=0;dt<4;dt++){
        #pragma unroll
        for(int m=0;m<8;m++){
          float oa1 = S.a1[dt][2*m]*rl1,   oa2 = S.a2[dt][2*m]*rl2;
          float ob1 = S.a1[dt][2*m+1]*rl1, ob2 = S.a2[dt][2*m+1]*rl2;
          float oa = oa1 + sh*(oa2-oa1);
          float ob = ob1 + sh*(ob2-ob1);
          int d = dt*32 + (2*m&3) + 8*(m>>1) + 4*l5;
          *(u32*)(obase + d) = cvtpk(oa, ob);
        }
      }
    }
    // seg1: tile 63-p, first half k[0, 31-p) -> partial to LDS
    run_seg(63-p, 0, 31-p, bh, b, h, l5, q31, Q, KF, VF, qp, kp, S);
    #pragma unroll
    for(int dt=0;dt<4;dt++){
      *(f32x16*)&lp1[(dt*64 + l)*16] = S.a1[dt];
      *(f32x16*)&lp2[(dt*64 + l)*16] = S.a2[dt];
    }
    if(l5==0){
      lml[q31*4+0] = S.m1; lml[q31*4+1] = S.l1;
      lml[q31*4+2] = S.m2; lml[q31*4+3] = S.l2;
    }
    __syncthreads();
  } else {
    // wave1: tile 63-p, second half k[31-p, 64-p)
    run_seg(63-p, 31-p, 64-p, bh, b, h, l5, q31, Q, KF, VF, qp, kp, S);
    __syncthreads();
    float mA1 = lml[q31*4+0], lA1 = lml[q31*4+1];
    float mA2 = lml[q31*4+2], lA2 = lml[q31*4+3];
    float M1 = fmaxf(mA1, S.m1), M2 = fmaxf(mA2, S.m2);
    float wA1 = exp2f(mA1-M1), wB1 = exp2f(S.m1-M1);
    float wA2 = exp2f(mA2-M2), wB2 = exp2f(S.m2-M2);
    float r1 = 1.0f/(wA1*lA1 + wB1*S.l1);
    float r2 = 1.0f/(wA2*lA2 + wB2*S.l2);
    int q = (63-p)*32 + q31;
    u16* obase = outp + (size_t)(b*TT + q)*CC + h*DD;
    #pragma unroll
    for(int dt=0;dt<4;dt++){
      f32x16 pa1 = *(const f32x16*)&lp1[(dt*64 + l)*16];
      f32x16 pa2 = *(const f32x16*)&lp2[(dt*64 + l)*16];
      #pragma unroll
      for(int m=0;m<8;m++){
        float oa1 = (wA1*pa1[2*m]   + wB1*S.a1[dt][2*m])*r1;
        float ob1 = (wA1*pa1[2*m+1] + wB1*S.a1[dt][2*m+1])*r1;
        float oa2 = (wA2*pa2[2*m]   + wB2*S.a2[dt][2*m])*r2;
        float ob2 = (wA2*pa2[2*m+1] + wB2*S.a2[dt][2*m+1])*r2;
        float oa = oa1 + sh*(oa2-oa1);
        float ob = ob1 + sh*(ob2-ob1);
        int d = dt*32 + (2*m&3) + 8*(m>>1) + 4*l5;
        *(u32*)(obase + d) = cvtpk(oa, ob);
      }
    }
  }
}

extern "C" void kernel_launch(void* const* d_in, const int* in_sizes, int n_in,
                              void* d_out, int out_size, void* d_ws, size_t ws_size,
                              hipStream_t stream){
  (void)in_sizes; (void)n_in; (void)out_size; (void)ws_size;
  const float* x   = (const float*)d_in[0];
  const float* Wq  = (const float*)d_in[1];
  const float* Wk  = (const float*)d_in[2];
  const float* Wv  = (const float*)d_in[3];
  const float* Wo  = (const float*)d_in[4];
  const float* lng = (const float*)d_in[5];
  const float* lnb = (const float*)d_in[6];
  const float* hsc = (const float*)d_in[7];
  const float* hdr = (const float*)d_in[8];

  char* ws = (char*)d_ws;
  const size_t MB = 1048576;
  u16* xn   = (u16*)ws;                 // 16MB (LN out, later attn out)
  u16* wbf  = (u16*)(ws + 16*MB);       // 8MB bf16 weights Wq|Wk|Wv|Wo
  u16* Qb   = (u16*)(ws + 24*MB);       // 16MB
  u16* Kb   = (u16*)(ws + 40*MB);       // 16MB raw K
  u16* VF   = (u16*)(ws + 56*MB);       // 16MB packed V fragments
  u16* KF   = (u16*)(ws + 72*MB);       // 16MB packed K fragments
  float* cosT = (float*)(ws + 88*MB);
  float* sinT = cosT + 131072;
  float* qp   = sinT + 131072;
  float* kp   = qp + 65536;

  ln_k<<<8192,256,0,stream>>>(x, lng, lnb, xn);
  wconv_k<<<4096,256,0,stream>>>(Wq,Wk,Wv,Wo,wbf);
  rope_tab_k<<<512,256,0,stream>>>(cosT,sinT);
  gemm_k<0><<<dim3(64,8),256,0,stream>>>(xn, wbf,          Qb, nullptr, nullptr);
  gemm_k<0><<<dim3(64,8),256,0,stream>>>(xn, wbf+1048576,  Kb, nullptr, nullptr);
  gemm_k<4><<<dim3(64,8),256,0,stream>>>(xn, wbf+2097152,  VF, nullptr, nullptr);
  qpkp_k<<<256,256,0,stream>>>(Qb,Kb,hdr,cosT,sinT,qp,kp);          // raw Q/K + local rope
  ropepack_k<<<8192,128,0,stream>>>(Qb,Kb,KF,cosT,sinT);            // Q in place (pre-scaled); K -> KF
  attn_k<<<1024,128,0,stream>>>(Qb,KF,VF,qp,kp,hsc,xn);
  gemm_k<2><<<dim3(64,8),256,0,stream>>>(xn, wbf+3145728, nullptr, (float*)d_out, x);
}

// Round 14
// 224.891 us; speedup vs baseline: 1.2369x; 1.0243x over previous
//
#include <hip/hip_runtime.h>
#include <hip/hip_bf16.h>
#include <stdint.h>

#define BB 4
#define TT 2048
#define CC 1024
#define HH 8
#define DD 128

typedef unsigned short u16;
typedef unsigned int u32;
typedef unsigned long long u64;
typedef __attribute__((ext_vector_type(4))) float f32x4;
typedef __attribute__((ext_vector_type(16))) float f32x16;
typedef __attribute__((ext_vector_type(8))) __bf16 bf16x8;

#define SL2C (0.08838834764831845f * 1.442695040888963f)   // 1/sqrt(128) * log2(e), folded into Q

__device__ __forceinline__ float bf2f(u16 u){ u32 x=((u32)u)<<16; float f; __builtin_memcpy(&f,&x,4); return f; }
__device__ __forceinline__ u16 f2bf(float f){ u32 x; __builtin_memcpy(&x,&f,4); x += 0x7fffu + ((x>>16)&1u); return (u16)(x>>16); }

__device__ __forceinline__ void gload16(const void* g, void* l){
  __builtin_amdgcn_global_load_lds((const __attribute__((address_space(1))) u32*)g,
                                   (__attribute__((address_space(3))) u32*)l, 16, 0, 0);
}
__device__ __forceinline__ f32x4 mfma16(bf16x8 a, bf16x8 b, f32x4 c){
  return __builtin_amdgcn_mfma_f32_16x16x32_bf16(a,b,c,0,0,0);
}
__device__ __forceinline__ f32x16 mfma32(bf16x8 a, bf16x8 b, f32x16 c){
  return __builtin_amdgcn_mfma_f32_32x32x16_bf16(a,b,c,0,0,0);
}
__device__ __forceinline__ u32 cvtpk(float lo, float hi){
  u32 r; asm("v_cvt_pk_bf16_f32 %0, %1, %2" : "=v"(r) : "v"(lo), "v"(hi)); return r;
}
__device__ __forceinline__ void pl32swap(u32& d, u32& s){
  asm volatile("v_permlane32_swap_b32 %0, %1" : "+v"(d), "+v"(s));
}
union FRAG { u32 u[4]; bf16x8 v; };

// ---------------- LayerNorm: f32 x -> bf16 xn ----------------
__global__ void ln_k(const float* __restrict__ x, const float* __restrict__ g,
                     const float* __restrict__ bta, u16* __restrict__ xn){
  int row = blockIdx.x, tid = threadIdx.x;
  const float4 v = ((const float4*)(x + (size_t)row*CC))[tid];
  float s = v.x+v.y+v.z+v.w;
  float ss = v.x*v.x+v.y*v.y+v.z*v.z+v.w*v.w;
  #pragma unroll
  for(int m=1;m<64;m<<=1){ s += __shfl_xor(s,m); ss += __shfl_xor(ss,m); }
  __shared__ float red[8];
  if((tid&63)==0){ red[tid>>6]=s; red[4+(tid>>6)]=ss; }
  __syncthreads();
  float ts = red[0]+red[1]+red[2]+red[3];
  float tss = red[4]+red[5]+red[6]+red[7];
  float mu = ts*(1.0f/CC);
  float rs = rsqrtf(tss*(1.0f/CC) - mu*mu + 1e-5f);
  int c0 = tid*4;
  ushort4 o;
  o.x = f2bf((v.x-mu)*rs*g[c0+0]+bta[c0+0]);
  o.y = f2bf((v.y-mu)*rs*g[c0+1]+bta[c0+1]);
  o.z = f2bf((v.z-mu)*rs*g[c0+2]+bta[c0+2]);
  o.w = f2bf((v.w-mu)*rs*g[c0+3]+bta[c0+3]);
  ((ushort4*)(xn + (size_t)row*CC))[tid] = o;
}

// ---------------- prep: weights f32->bf16 (blocks 0..4095) + RoPE tables (blocks 4096..4607) ----------------
__global__ void prep_k(const float* __restrict__ wq, const float* __restrict__ wk,
                       const float* __restrict__ wv, const float* __restrict__ wo,
                       u16* __restrict__ out, float* __restrict__ cosT, float* __restrict__ sinT){
  if(blockIdx.x < 4096){
    int i = blockIdx.x*256 + threadIdx.x;
    int sel = i>>18;
    const float* src = sel==0?wq: sel==1?wk: sel==2?wv:wo;
    float4 v = ((const float4*)src)[i & 262143];
    ushort4 o; o.x=f2bf(v.x); o.y=f2bf(v.y); o.z=f2bf(v.z); o.w=f2bf(v.w);
    ((ushort4*)out)[i] = o;
  } else {
    int i = (blockIdx.x-4096)*256 + threadIdx.x;  // 131072
    int t = i>>6, j = i&63;
    float inv = powf(10000.0f, -(float)(2*j)*(1.0f/128.0f));
    float a = (float)t * inv;
    cosT[i] = cosf(a);
    sinT[i] = sinf(a);
  }
}

// ---------------- qp/kp from ROPED Q (prescaled) and ROPED KF ----------------
__global__ void qpkp_k(const u16* __restrict__ Qb, const u16* __restrict__ KF,
                       const float* __restrict__ dirs, float* __restrict__ qp, float* __restrict__ kp){
  const float INV_SL2 = 1.0f/SL2C;
  int idx = blockIdx.x*256 + threadIdx.x;   // (b*H+h)*T + t
  int b = idx>>14, rem = idx & 16383;
  int h = rem>>11, t = rem & 2047;
  int bh = b*HH + h;
  float d0 = dirs[h*3], d1 = dirs[h*3+1], d2 = dirs[h*3+2];
  size_t qbase = ((size_t)(b*TT + t))*CC + h*DD;
  qp[idx] = (bf2f(Qb[qbase])*d0 + bf2f(Qb[qbase+1])*d1 + bf2f(Qb[qbase+2])*d2) * INV_SL2;
  // KF frag: d in {0,1,2} -> (d>>4)=0, (d>>3)&1=0, (d&7)=d  => base + t31*8 + d
  size_t kb = ((size_t)(bh*64 + (t>>5))*8)*512 + (size_t)(t&31)*8;
  kp[idx] = bf2f(KF[kb])*d0 + bf2f(KF[kb+1])*d1 + bf2f(KF[kb+2])*d2;
}

// ---------------- GEMM ----------------
// MODE 0: Q: rope + SL2 prescale -> row-major Qb. MODE 5: K: rope -> fragment-packed KF.
// MODE 4: V -> fragment-packed VF. MODE 2: f32 out + residual.
template<int MODE>
__global__ __launch_bounds__(256) void gemm_k(const u16* __restrict__ A, const u16* __restrict__ W,
                                              u16* __restrict__ outb, float* __restrict__ outf,
                                              const float* __restrict__ resid,
                                              const float* __restrict__ cosT, const float* __restrict__ sinT){
  __shared__ __align__(16) u16 sbuf[16384];   // main loop: As=sbuf[0:8192), Bs=[8192:16384); epilogue: 128x128 stage
  u16* As = sbuf;
  u16* Bs = sbuf + 8192;
  const int K = CC;
  int m0 = blockIdx.x*128, n0 = blockIdx.y*128;
  int tid = threadIdx.x, w = tid>>6, l = tid&63;
  int li = l&15, lg = l>>4;
  int wm = w>>1, wn = w&1;
  f32x4 acc[4][4] = {};
  for(int k0=0; k0<K; k0+=64){
    #pragma unroll
    for(int i=0;i<4;i++){
      int L = (w*4+i)*1024 + l*16;
      int row = L>>7;
      int colb = (L&127) ^ ((row&7)<<4);
      gload16(A + ((size_t)(m0+row)*K + k0 + (colb>>1)), (char*)As + (w*4+i)*1024);
      gload16(W + ((size_t)(n0+row)*K + k0 + (colb>>1)), (char*)Bs + (w*4+i)*1024);
    }
    __syncthreads();
    #pragma unroll
    for(int kc=0;kc<2;kc++){
      bf16x8 af[4], bfr[4];
      #pragma unroll
      for(int mi=0;mi<4;mi++){
        int row = wm*64 + mi*16 + li;
        int colb = (kc*64 + lg*16) ^ ((row&7)<<4);
        af[mi] = *(const bf16x8*)((const char*)As + row*128 + colb);
      }
      #pragma unroll
      for(int ni=0;ni<4;ni++){
        int row = wn*64 + ni*16 + li;
        int colb = (kc*64 + lg*16) ^ ((row&7)<<4);
        bfr[ni] = *(const bf16x8*)((const char*)Bs + row*128 + colb);
      }
      #pragma unroll
      for(int mi=0;mi<4;mi++){
        #pragma unroll
        for(int ni=0;ni<4;ni++)
          acc[mi][ni] = mfma16(af[mi], bfr[ni], acc[mi][ni]);
      }
    }
    __syncthreads();
  }

  if(MODE==0 || MODE==5){
    // ---- fused RoPE epilogue: stage bf16 acc in LDS, exchange (d, d^64), rope, pack out ----
    // (numerically identical to old path: GEMM-out was bf16-rounded before the rope pass)
    #pragma unroll
    for(int mi=0;mi<4;mi++){
      #pragma unroll
      for(int ni=0;ni<4;ni++){
        int c = wn*64 + ni*16 + li;
        #pragma unroll
        for(int r=0;r<4;r++){
          int rr = wm*64 + mi*16 + lg*4 + r;
          sbuf[rr*128 + (c ^ ((rr&15)<<3))] = f2bf(acc[mi][ni][r]);   // XOR swizzle both sides
        }
      }
    }
    __syncthreads();
    int rowl = tid & 127, half = tid >> 7;    // thread -> (row, col-half); 16 x 4-col groups each
    int grow = m0 + rowl;
    int t = grow & (TT-1);
    int swz = (rowl&15)<<3;
    const float* cbase = cosT + t*64;
    const float* sbase = sinT + t*64;
    #pragma unroll
    for(int g=0; g<16; g++){
      int c0 = half*64 + g*4;
      int j0 = c0 & 63;
      float4 cv = *(const float4*)(cbase + j0);
      float4 sv4 = *(const float4*)(sbase + j0);
      ushort4 se4 = *(const ushort4*)&sbuf[rowl*128 + (c0 ^ swz)];
      ushort4 pa4 = *(const ushort4*)&sbuf[rowl*128 + ((c0^64) ^ swz)];
      float se[4] = {bf2f(se4.x),bf2f(se4.y),bf2f(se4.z),bf2f(se4.w)};
      float pa[4] = {bf2f(pa4.x),bf2f(pa4.y),bf2f(pa4.z),bf2f(pa4.w)};
      float cc4[4] = {cv.x,cv.y,cv.z,cv.w};
      float ss4[4] = {sv4.x,sv4.y,sv4.z,sv4.w};
      ushort4 o; u16* op = (u16*)&o;
      #pragma unroll
      for(int e=0;e<4;e++){
        float v = half ? (se[e]*cc4[e] + pa[e]*ss4[e]) : (se[e]*cc4[e] - pa[e]*ss4[e]);
        if(MODE==0) v *= SL2C;
        op[e] = f2bf(v);
      }
      if(MODE==0){
        *(ushort4*)(outb + (size_t)grow*CC + n0 + c0) = o;
      } else {
        int b = grow>>11;
        int h = n0>>7;                       // one head per 128-col tile
        int bh = b*HH + h;
        int d0 = c0;
        size_t of = (((size_t)(bh*64 + (t>>5))*8) + (d0>>4))*512 + (((d0>>3)&1)*32 + (t&31))*8 + (d0&7);
        *(ushort4*)(outb + of) = o;
      }
    }
    return;
  }

  #pragma unroll
  for(int mi=0;mi<4;mi++){
    #pragma unroll
    for(int ni=0;ni<4;ni++){
      if(MODE==4){
        int row0 = m0 + wm*64 + mi*16 + lg*4;
        int col = n0 + wn*64 + ni*16 + li;
        int t = row0 & 2047, b = row0>>11;
        int h = col>>7, d = col&127;
        int bh = b*HH + h;
        size_t o = (((size_t)(bh*64 + (t>>5))*8) + (d>>5)*2 + ((t>>4)&1))*512
                   + (((t>>3)&1)*32 + (d&31))*8 + (t&7);
        ushort4 pk;
        pk.x = f2bf(acc[mi][ni][0]); pk.y = f2bf(acc[mi][ni][1]);
        pk.z = f2bf(acc[mi][ni][2]); pk.w = f2bf(acc[mi][ni][3]);
        *(ushort4*)(outb + o) = pk;
      } else {
        #pragma unroll
        for(int r=0;r<4;r++){
          int row = m0 + wm*64 + mi*16 + lg*4 + r;
          int col = n0 + wn*64 + ni*16 + li;
          size_t o = (size_t)row*CC + col;
          outf[o] = acc[mi][ni][r] + resid[o];
        }
      }
    }
  }
}

// ---------------- attention segment state + inner loop (R11/R13-proven body, Q pre-scaled) ----------------
struct SegState { float m1, l1, m2, l2; f32x16 a1[4]; f32x16 a2[4]; };

__device__ __forceinline__ void run_seg(int t, int klo, int khi, int bh, int b, int h,
                                        int l5, int q31,
                                        const u16* __restrict__ Q, const u16* __restrict__ KF,
                                        const u16* __restrict__ VF, const float* __restrict__ qp,
                                        const float* __restrict__ kp, SegState& S){
  const f32x16 zf = {};
  S.m1 = -__builtin_inff(); S.l1 = 0.f; S.m2 = -__builtin_inff(); S.l2 = 0.f;
  #pragma unroll
  for(int dt=0;dt<4;dt++){ S.a1[dt] = zf; S.a2[dt] = zf; }
  if(khi <= klo) return;

  int q0 = t*32, q = q0 + q31;
  bf16x8 qf[8];
  {
    const u16* qbase = Q + ((size_t)(b*TT + q)*CC + h*DD);
    #pragma unroll
    for(int db=0;db<8;db++) qf[db] = *(const bf16x8*)(qbase + db*16 + l5*8);
  }
  const float L2E = 1.442695040888963f;
  bf16x8 qpf;
  {
    float qs = qp[(size_t)bh*TT + q] * L2E;
    u16 qh = f2bf(qs); float qhf = bf2f(qh);
    u16 ql = f2bf(qs - qhf);
    FRAG fq; fq.u[0] = l5? 0u : ((u32)qh | ((u32)qh<<16));
    fq.u[1] = l5? 0u : (u32)ql; fq.u[2]=0; fq.u[3]=0;
    qpf = fq.v;
  }
  const u16* kfp = KF + (size_t)bh*64*4096 + (size_t)klo*4096 + (size_t)(q31 + 32*l5)*8;
  const u16* vfp = VF + (size_t)bh*64*4096 + (size_t)klo*4096 + (size_t)(q31 + 32*l5)*8;
  const float* kpp = kp + (size_t)bh*TT + q31;

  for(int is=klo; is<khi; ++is){
    int ksub = is*32;

    bf16x8 kf0 = *(const bf16x8*)(kfp + 0*512);
    bf16x8 kf1 = *(const bf16x8*)(kfp + 1*512);
    bf16x8 kf2 = *(const bf16x8*)(kfp + 2*512);
    bf16x8 kf3 = *(const bf16x8*)(kfp + 3*512);
    bf16x8 kf4 = *(const bf16x8*)(kfp + 4*512);
    bf16x8 kf5 = *(const bf16x8*)(kfp + 5*512);
    bf16x8 kf6 = *(const bf16x8*)(kfp + 6*512);
    bf16x8 kf7 = *(const bf16x8*)(kfp + 7*512);

    f32x16 s0 = {}, s1a = {};
    __builtin_amdgcn_s_setprio(1);
    s0  = mfma32(kf0, qf[0], s0);  s1a = mfma32(kf1, qf[1], s1a);
    s0  = mfma32(kf2, qf[2], s0);  s1a = mfma32(kf3, qf[3], s1a);
    s0  = mfma32(kf4, qf[4], s0);  s1a = mfma32(kf5, qf[5], s1a);
    s0  = mfma32(kf6, qf[6], s0);  s1a = mfma32(kf7, qf[7], s1a);
    __builtin_amdgcn_s_setprio(0);

    f32x16 gg;
    {
      const f32x16 zf2 = {};
      float kpv = kpp[ksub];
      u16 kh = f2bf(kpv); float khf = bf2f(kh);
      u16 kl = f2bf(kpv - khf);
      FRAG fk; fk.u[0] = l5? 0u : ((u32)kh | ((u32)kl<<16));
      fk.u[1] = l5? 0u : (u32)kh; fk.u[2]=0; fk.u[3]=0;
      gg = mfma32(fk.v, qpf, zf2);
    }

    float sv[16], gv[16];
    #pragma unroll
    for(int rr=0;rr<16;rr++){ sv[rr] = s0[rr]+s1a[rr]; gv[rr] = gg[rr]; }   // Q pre-scaled: log2 domain
    if(ksub + 31 > q0){                       // wave-uniform diagonal test
      #pragma unroll
      for(int rr=0;rr<16;rr++){
        int kg = ksub + (rr&3) + 8*(rr>>2) + 4*l5;
        if(kg > q){ sv[rr] = -__builtin_inff(); gv[rr] = -__builtin_inff(); }
      }
    }

    float mx=-__builtin_inff(), gx=-__builtin_inff();
    #pragma unroll
    for(int rr=0;rr<16;rr++){ mx = fmaxf(mx, sv[rr]); gx = fmaxf(gx, gv[rr]); }
    mx = fmaxf(mx, __shfl_xor(mx,32));
    gx = fmaxf(gx, __shfl_xor(gx,32));
    if(__ballot((mx > S.m1+8.f) | (gx > S.m2+8.f))){
      float mn1 = fmaxf(S.m1,mx), mn2 = fmaxf(S.m2,gx);
      float c1 = exp2f(S.m1-mn1), c2 = exp2f(S.m2-mn2);
      S.l1 *= c1; S.l2 *= c2; S.m1 = mn1; S.m2 = mn2;
      #pragma unroll
      for(int dt=0;dt<4;dt++){ S.a1[dt] *= c1; S.a2[dt] *= c2; }
    }
    float rs1=0.f, rs2=0.f;
    float e1[16], e2[16];
    #pragma unroll
    for(int rr=0;rr<16;rr++){
      e1[rr] = exp2f(sv[rr] - S.m1); rs1 += e1[rr];
      e2[rr] = exp2f(gv[rr] - S.m2); rs2 += e2[rr];
    }
    rs1 += __shfl_xor(rs1,32); rs2 += __shfl_xor(rs2,32);
    S.l1 += rs1; S.l2 += rs2;

    u32 P1[8], P2[8];
    #pragma unroll
    for(int m=0;m<8;m++){ P1[m] = cvtpk(e1[2*m], e1[2*m+1]); P2[m] = cvtpk(e2[2*m], e2[2*m+1]); }
    pl32swap(P1[0],P1[2]); pl32swap(P1[1],P1[3]); pl32swap(P1[4],P1[6]); pl32swap(P1[5],P1[7]);
    pl32swap(P2[0],P2[2]); pl32swap(P2[1],P2[3]); pl32swap(P2[4],P2[6]); pl32swap(P2[5],P2[7]);

    #pragma unroll
    for(int kb2=0;kb2<2;kb2++){
      FRAG f1, f2;
      #pragma unroll
      for(int j2=0;j2<4;j2++){ f1.u[j2] = P1[kb2*4+j2]; f2.u[j2] = P2[kb2*4+j2]; }
      bf16x8 pb1 = f1.v, pb2 = f2.v;
      bf16x8 vf0 = *(const bf16x8*)(vfp + (0+kb2)*512);
      bf16x8 vf1 = *(const bf16x8*)(vfp + (2+kb2)*512);
      bf16x8 vf2 = *(const bf16x8*)(vfp + (4+kb2)*512);
      bf16x8 vf3 = *(const bf16x8*)(vfp + (6+kb2)*512);
      __builtin_amdgcn_s_setprio(1);
      S.a1[0] = mfma32(vf0, pb1, S.a1[0]);  S.a2[0] = mfma32(vf0, pb2, S.a2[0]);
      S.a1[1] = mfma32(vf1, pb1, S.a1[1]);  S.a2[1] = mfma32(vf1, pb2, S.a2[1]);
      S.a1[2] = mfma32(vf2, pb1, S.a1[2]);  S.a2[2] = mfma32(vf2, pb2, S.a2[2]);
      S.a1[3] = mfma32(vf3, pb1, S.a1[3]);  S.a2[3] = mfma32(vf3, pb2, S.a2[3]);
      __builtin_amdgcn_s_setprio(0);
    }
    kfp += 4096; vfp += 4096;
  }
}

// ---------------- fused dual flash attention: pair-balanced waves + in-block LDS merge (R9/R13-proven) ----------------
// NOTE: keep __launch_bounds__(128,2) — combined VGPR+AGPR/wave ~256 (unified file): 3/EU spills (R6/R7);
// prefetch machinery bloats VGPR to 208 and halves occupancy (R12). Do not touch.
__global__ __launch_bounds__(128,2) void attn_k(const u16* __restrict__ Q, const u16* __restrict__ KF,
                                                const u16* __restrict__ VF, const float* __restrict__ qp,
                                                const float* __restrict__ kp, const float* __restrict__ hs,
                                                u16* __restrict__ outp){
  __shared__ __align__(16) float lp1[4*64*16];   // wave0's partial a1 [dt][lane][r]
  __shared__ __align__(16) float lp2[4*64*16];   // partial a2
  __shared__ float lml[32*4];                    // per q31: m1,l1,m2,l2
  int bid = blockIdx.x;
  int xcd = bid&7, r = bid>>3;          // r: 0..127
  int bh = xcd*4 + (r&3);               // 4 bh groups per XCD
  int p = r>>2;                         // 0..31 pair index
  int b = bh>>3, h = bh&7;
  int tid = threadIdx.x, w = tid>>6, l = tid&63;
  int l5 = l>>5, q31 = l&31;
  float sh = hs[h];

  SegState S;
  if(w==0){
    // seg0: tile p, full range, direct write
    run_seg(p, 0, p+1, bh, b, h, l5, q31, Q, KF, VF, qp, kp, S);
    {
      float rl1 = 1.0f/S.l1, rl2 = 1.0f/S.l2;
      int q = p*32 + q31;
      u16* obase = outp + (size_t)(b*TT + q)*CC + h*DD;
      #pragma unroll
      for(int dt=0;dt<4;dt++){
        #pragma unroll
        for(int m=0;m<8;m++){
          float oa1 = S.a1[dt][2*m]*rl1,   oa2 = S.a2[dt][2*m]*rl2;
          float ob1 = S.a1[dt][2*m+1]*rl1, ob2 = S.a2[dt][2*m+1]*rl2;
          float oa = oa1 + sh*(oa2-oa1);
          float ob = ob1 + sh*(ob2-ob1);
          int d = dt*32 + (2*m&3) + 8*(m>>1) + 4*l5;
          *(u32*)(obase + d) = cvtpk(oa, ob);
        }
      }
    }
    // seg1: tile 63-p, first half k[0, 31-p) -> partial to LDS
    run_seg(63-p, 0, 31-p, bh, b, h, l5, q31, Q, KF, VF, qp, kp, S);
    #pragma unroll
    for(int dt=0;dt<4;dt++){
      *(f32x16*)&lp1[(dt*64 + l)*16] = S.a1[dt];
      *(f32x16*)&lp2[(dt*64 + l)*16] = S.a2[dt];
    }
    if(l5==0){
      lml[q31*4+0] = S.m1; lml[q31*4+1] = S.l1;
      lml[q31*4+2] = S.m2; lml[q31*4+3] = S.l2;
    }
    __syncthreads();
  } else {
    // wave1: tile 63-p, second half k[31-p, 64-p)
    run_seg(63-p, 31-p, 64-p, bh, b, h, l5, q31, Q, KF, VF, qp, kp, S);
    __syncthreads();
    float mA1 = lml[q31*4+0], lA1 = lml[q31*4+1];
    float mA2 = lml[q31*4+2], lA2 = lml[q31*4+3];
    float M1 = fmaxf(mA1, S.m1), M2 = fmaxf(mA2, S.m2);
    float wA1 = exp2f(mA1-M1), wB1 = exp2f(S.m1-M1);
    float wA2 = exp2f(mA2-M2), wB2 = exp2f(S.m2-M2);
    float r1 = 1.0f/(wA1*lA1 + wB1*S.l1);
    float r2 = 1.0f/(wA2*lA2 + wB2*S.l2);
    int q = (63-p)*32 + q31;
    u16* obase = outp + (size_t)(b*TT + q)*CC + h*DD;
    #pragma unroll
    for(int dt=0;dt<4;dt++){
      f32x16 pa1 = *(const f32x16*)&lp1[(dt*64 + l)*16];
      f32x16 pa2 = *(const f32x16*)&lp2[(dt*64 + l)*16];
      #pragma unroll
      for(int m=0;m<8;m++){
        float oa1 = (wA1*pa1[2*m]   + wB1*S.a1[dt][2*m])*r1;
        float ob1 = (wA1*pa1[2*m+1] + wB1*S.a1[dt][2*m+1])*r1;
        float oa2 = (wA2*pa2[2*m]   + wB2*S.a2[dt][2*m])*r2;
        float ob2 = (wA2*pa2[2*m+1] + wB2*S.a2[dt][2*m+1])*r2;
        float oa = oa1 + sh*(oa2-oa1);
        float ob = ob1 + sh*(ob2-ob1);
        int d = dt*32 + (2*m&3) + 8*(m>>1) + 4*l5;
        *(u32*)(obase + d) = cvtpk(oa, ob);
      }
    }
  }
}

extern "C" void kernel_launch(void* const* d_in, const int* in_sizes, int n_in,
                              void* d_out, int out_size, void* d_ws, size_t ws_size,
                              hipStream_t stream){
  (void)in_sizes; (void)n_in; (void)out_size; (void)ws_size;
  const float* x   = (const float*)d_in[0];
  const float* Wq  = (const float*)d_in[1];
  const float* Wk  = (const float*)d_in[2];
  const float* Wv  = (const float*)d_in[3];
  const float* Wo  = (const float*)d_in[4];
  const float* lng = (const float*)d_in[5];
  const float* lnb = (const float*)d_in[6];
  const float* hsc = (const float*)d_in[7];
  const float* hdr = (const float*)d_in[8];

  char* ws = (char*)d_ws;
  const size_t MB = 1048576;
  u16* xn   = (u16*)ws;                 // 16MB (LN out, later attn out)
  u16* wbf  = (u16*)(ws + 16*MB);       // 8MB bf16 weights Wq|Wk|Wv|Wo
  u16* Qb   = (u16*)(ws + 24*MB);       // 16MB roped+prescaled Q
  u16* VF   = (u16*)(ws + 56*MB);       // 16MB packed V fragments
  u16* KF   = (u16*)(ws + 72*MB);       // 16MB packed roped K fragments
  float* cosT = (float*)(ws + 88*MB);
  float* sinT = cosT + 131072;
  float* qp   = sinT + 131072;
  float* kp   = qp + 65536;

  ln_k<<<8192,256,0,stream>>>(x, lng, lnb, xn);
  prep_k<<<4608,256,0,stream>>>(Wq,Wk,Wv,Wo,wbf,cosT,sinT);
  gemm_k<0><<<dim3(64,8),256,0,stream>>>(xn, wbf,          Qb, nullptr, nullptr, cosT, sinT);  // Q + rope + prescale
  gemm_k<5><<<dim3(64,8),256,0,stream>>>(xn, wbf+1048576,  KF, nullptr, nullptr, cosT, sinT);  // K + rope -> KF
  gemm_k<4><<<dim3(64,8),256,0,stream>>>(xn, wbf+2097152,  VF, nullptr, nullptr, nullptr, nullptr);
  qpkp_k<<<256,256,0,stream>>>(Qb,KF,hdr,qp,kp);
  attn_k<<<1024,128,0,stream>>>(Qb,KF,VF,qp,kp,hsc,xn);
  gemm_k<2><<<dim3(64,8),256,0,stream>>>(xn, wbf+3145728, nullptr, (float*)d_out, x, nullptr, nullptr);
}